// Round 2
// baseline (123.335 us; speedup 1.0000x reference)
//
#include <hip/hip_runtime.h>

// Problem constants: B=16, C=1, H=768, W=768, K=512
#define BDIM 16
#define HDIM 768
#define WDIM 768
#define KCOR 512
constexpr int HW = HDIM * WDIM;            // 589824
constexpr int TOTAL = BDIM * HW;           // 9437184
// Each thread handles 8 consecutive elements (two float4s). 768 % 8 == 0 so a
// span never crosses a row boundary.
constexpr int NTHREADS_TOT = TOTAL / 8;    // 1179648
constexpr int BLOCK = 256;
constexpr int NBLK = NTHREADS_TOT / BLOCK; // 4608

// ---------------------------------------------------------------------------
// Fused kernel:
//  * all blocks: streaming sum of (peak + (gt>0?5:1)) * (pre-gt)^2 over an
//    8-element span per thread. Neighbor loads are ADDRESS-CLAMPED and
//    unconditional (then value-selected to 0) so there are no branches around
//    loads -> full pipelining of the load latency.
//  * blocks 0..15 additionally compute the gt-scatter XOR correction
//    (1 - 2*peak)*err at each UNIQUE gt coordinate of batch b=blockIdx.x
//    (O(K^2) LDS dedup; duplicates contribute once, order irrelevant).
//  * per-block partial written to ws[blockIdx] (no atomics, no memset needed).
// ---------------------------------------------------------------------------
__global__ __launch_bounds__(BLOCK) void fused_kernel(
    const float* __restrict__ pre,
    const float* __restrict__ gt,
    const int* __restrict__ cors,    // (B, K, 2) as [x, y]
    float* __restrict__ ws_partials) {

    __shared__ int scoord[KCOR];
    __shared__ float lred[BLOCK / 64];

    float acc = 0.0f;

    // ---- correction work for blocks 0..15 (one per batch image) ----
    if (blockIdx.x < BDIM) {
        const int b = blockIdx.x;
        for (int k = threadIdx.x; k < KCOR; k += BLOCK) {
            const int x = cors[(b * KCOR + k) * 2 + 0];
            const int y = cors[(b * KCOR + k) * 2 + 1];
            scoord[k] = y * WDIM + x;
        }
        __syncthreads();
        for (int k = threadIdx.x; k < KCOR; k += BLOCK) {
            const int packed = scoord[k];
            bool dup = false;
            for (int k2 = 0; k2 < k; ++k2) dup |= (scoord[k2] == packed);
            if (!dup) {
                const int y = packed / WDIM;
                const int x = packed - y * WDIM;
                const int idx = b * HW + packed;
                const float c = pre[idx];
                const float l = (x > 0)        ? pre[idx - 1]    : 0.0f;
                const float r = (x < WDIM - 1) ? pre[idx + 1]    : 0.0f;
                const float u = (y > 0)        ? pre[idx - WDIM] : 0.0f;
                const float d = (y < HDIM - 1) ? pre[idx + WDIM] : 0.0f;
                const bool peak = (c > l) && (c > r) && (c > u) && (c > d);
                float e = c - gt[idx];
                e *= e;
                acc += (peak ? -1.0f : 1.0f) * e;
            }
        }
        __syncthreads();   // scoord reuse barrier (none after, but keeps LDS clean)
    }

    // ---- streaming pass: 8 consecutive elements per thread ----
    {
        const int t   = blockIdx.x * BLOCK + threadIdx.x;
        const int idx = t * 8;                 // flat element index, 32B aligned
        const int rem = idx % HW;
        const int row = rem / WDIM;
        const int x   = rem % WDIM;            // multiple of 8

        // address-clamped, unconditional loads
        const int uoff = (row > 0)         ? WDIM : 0;
        const int doff = (row < HDIM - 1)  ? WDIM : 0;
        const int loff = (x > 0)           ? 1 : 0;
        const int roff = (x + 8 < WDIM)    ? 8 : 0;

        const float4 c0 = *(const float4*)(pre + idx);
        const float4 c1 = *(const float4*)(pre + idx + 4);
        const float4 g0 = *(const float4*)(gt  + idx);
        const float4 g1 = *(const float4*)(gt  + idx + 4);
        const float4 ua = *(const float4*)(pre + idx - uoff);
        const float4 ub = *(const float4*)(pre + idx + 4 - uoff);
        const float4 da = *(const float4*)(pre + idx + doff);
        const float4 db = *(const float4*)(pre + idx + 4 + doff);
        const float  lraw = pre[idx - loff];
        const float  rraw = pre[idx + roff];

        const bool hasu = (uoff != 0), hasd = (doff != 0);
        const float lft = (loff != 0) ? lraw : 0.0f;
        const float rgt = (roff != 0) ? rraw : 0.0f;

        const float c[8] = {c0.x, c0.y, c0.z, c0.w, c1.x, c1.y, c1.z, c1.w};
        const float g[8] = {g0.x, g0.y, g0.z, g0.w, g1.x, g1.y, g1.z, g1.w};
        const float u[8] = {hasu ? ua.x : 0.f, hasu ? ua.y : 0.f,
                            hasu ? ua.z : 0.f, hasu ? ua.w : 0.f,
                            hasu ? ub.x : 0.f, hasu ? ub.y : 0.f,
                            hasu ? ub.z : 0.f, hasu ? ub.w : 0.f};
        const float d[8] = {hasd ? da.x : 0.f, hasd ? da.y : 0.f,
                            hasd ? da.z : 0.f, hasd ? da.w : 0.f,
                            hasd ? db.x : 0.f, hasd ? db.y : 0.f,
                            hasd ? db.z : 0.f, hasd ? db.w : 0.f};
        const float lr[10] = {lft, c[0], c[1], c[2], c[3],
                              c[4], c[5], c[6], c[7], rgt};

        #pragma unroll
        for (int j = 0; j < 8; ++j) {
            const bool peak = (c[j] > lr[j]) && (c[j] > lr[j + 2]) &&
                              (c[j] > u[j]) && (c[j] > d[j]);
            float e = c[j] - g[j];
            e *= e;
            const float wt = (g[j] > 0.0f ? 5.0f : 1.0f) + (peak ? 1.0f : 0.0f);
            acc += wt * e;
        }
    }

    // ---- block reduction -> one partial per block ----
    #pragma unroll
    for (int off = 32; off > 0; off >>= 1) acc += __shfl_down(acc, off);
    const int wave = threadIdx.x >> 6;
    const int lane = threadIdx.x & 63;
    if (lane == 0) lred[wave] = acc;
    __syncthreads();
    if (threadIdx.x == 0) {
        float s = 0.0f;
        #pragma unroll
        for (int i = 0; i < BLOCK / 64; ++i) s += lred[i];
        ws_partials[blockIdx.x] = s;
    }
}

// ---------------------------------------------------------------------------
// Final reduce: NBLK partials -> scalar, scaled by 1/B.
// ---------------------------------------------------------------------------
__global__ __launch_bounds__(BLOCK) void reduce_kernel(
    const float* __restrict__ ws_partials,
    float* __restrict__ out) {
    float acc = 0.0f;
    for (int i = threadIdx.x; i < NBLK; i += BLOCK) acc += ws_partials[i];
    #pragma unroll
    for (int off = 32; off > 0; off >>= 1) acc += __shfl_down(acc, off);
    __shared__ float lred[BLOCK / 64];
    const int wave = threadIdx.x >> 6;
    const int lane = threadIdx.x & 63;
    if (lane == 0) lred[wave] = acc;
    __syncthreads();
    if (threadIdx.x == 0) {
        float s = 0.0f;
        #pragma unroll
        for (int i = 0; i < BLOCK / 64; ++i) s += lred[i];
        out[0] = s * (1.0f / (float)BDIM);
    }
}

extern "C" void kernel_launch(void* const* d_in, const int* in_sizes, int n_in,
                              void* d_out, int out_size, void* d_ws, size_t ws_size,
                              hipStream_t stream) {
    const float* pre  = (const float*)d_in[0];   // (16,1,768,768) fp32
    const float* gt   = (const float*)d_in[1];   // (16,1,768,768) fp32
    const int*   cors = (const int*)d_in[2];     // (16,512,2) int32
    float* out = (float*)d_out;                  // fp32 scalar
    float* partials = (float*)d_ws;              // NBLK floats of scratch

    fused_kernel<<<NBLK, BLOCK, 0, stream>>>(pre, gt, cors, partials);
    reduce_kernel<<<1, BLOCK, 0, stream>>>(partials, out);
}

// Round 3
// 123.013 us; speedup vs baseline: 1.0026x; 1.0026x over previous
//
#include <hip/hip_runtime.h>

// Problem constants: B=16, C=1, H=768, W=768, K=512
#define BDIM 16
#define HDIM 768
#define WDIM 768
#define KCOR 512
constexpr int HW = HDIM * WDIM;            // 589824
constexpr int TOTAL = BDIM * HW;           // 9437184
// Each thread handles 8 consecutive elements (two float4s). 768 % 8 == 0 so a
// span never crosses a row boundary.
constexpr int NTHREADS_TOT = TOTAL / 8;    // 1179648
constexpr int BLOCK = 256;
constexpr int NBLK = NTHREADS_TOT / BLOCK; // 4608
constexpr int NXCD = 8;
constexpr int BLK_PER_XCD = NBLK / NXCD;   // 576 blocks = exactly 2 images

// ---------------------------------------------------------------------------
// Fused kernel (round 3: XCD-aware swizzle for L2 locality).
//
// Streaming part: sum of (peak + (gt>0?5:1)) * (pre-gt)^2, 8 elems/thread,
// address-clamped unconditional neighbor loads (branchless, pipelined).
//
// XCD swizzle: hardware round-robins blockIdx across the 8 XCDs (b % 8).
// vb = (b & 7) * 576 + (b >> 3) gives XCD i the contiguous block range
// [i*576, (i+1)*576) = exactly 2 complete images, so the 3x re-read of pre
// rows (center/up/down) hits that XCD's private 4 MiB L2 instead of HBM.
// Images are independent (peak padding never crosses images) -> zero
// cross-XCD sharing.
//
// Correction part (raw blockIdx 0..15, spread 2 per XCD): at each UNIQUE gt
// coordinate the XOR flips peak-mask membership, contributing
// (1 - 2*peak)*err on top of the streaming base sum. O(K^2) LDS dedup.
// ---------------------------------------------------------------------------
__global__ __launch_bounds__(BLOCK) void fused_kernel(
    const float* __restrict__ pre,
    const float* __restrict__ gt,
    const int* __restrict__ cors,    // (B, K, 2) as [x, y]
    float* __restrict__ ws_partials) {

    __shared__ int scoord[KCOR];
    __shared__ float lred[BLOCK / 64];

    float acc = 0.0f;

    // ---- correction work for raw blocks 0..15 (one per batch image) ----
    if (blockIdx.x < BDIM) {
        const int b = blockIdx.x;
        for (int k = threadIdx.x; k < KCOR; k += BLOCK) {
            const int x = cors[(b * KCOR + k) * 2 + 0];
            const int y = cors[(b * KCOR + k) * 2 + 1];
            scoord[k] = y * WDIM + x;
        }
        __syncthreads();
        for (int k = threadIdx.x; k < KCOR; k += BLOCK) {
            const int packed = scoord[k];
            bool dup = false;
            for (int k2 = 0; k2 < k; ++k2) dup |= (scoord[k2] == packed);
            if (!dup) {
                const int y = packed / WDIM;
                const int x = packed - y * WDIM;
                const int idx = b * HW + packed;
                const float c = pre[idx];
                const float l = (x > 0)        ? pre[idx - 1]    : 0.0f;
                const float r = (x < WDIM - 1) ? pre[idx + 1]    : 0.0f;
                const float u = (y > 0)        ? pre[idx - WDIM] : 0.0f;
                const float d = (y < HDIM - 1) ? pre[idx + WDIM] : 0.0f;
                const bool peak = (c > l) && (c > r) && (c > u) && (c > d);
                float e = c - gt[idx];
                e *= e;
                acc += (peak ? -1.0f : 1.0f) * e;
            }
        }
    }

    // ---- streaming pass: 8 consecutive elements per thread ----
    {
        // XCD-locality swizzle (bijection on [0, NBLK))
        const int vb  = (blockIdx.x & (NXCD - 1)) * BLK_PER_XCD + (blockIdx.x >> 3);
        const int t   = vb * BLOCK + threadIdx.x;
        const int idx = t * 8;                 // flat element index, 32B aligned
        const int rem = idx % HW;
        const int row = rem / WDIM;
        const int x   = rem % WDIM;            // multiple of 8

        // address-clamped, unconditional loads
        const int uoff = (row > 0)         ? WDIM : 0;
        const int doff = (row < HDIM - 1)  ? WDIM : 0;
        const int loff = (x > 0)           ? 1 : 0;
        const int roff = (x + 8 < WDIM)    ? 8 : 0;

        const float4 c0 = *(const float4*)(pre + idx);
        const float4 c1 = *(const float4*)(pre + idx + 4);
        const float4 g0 = *(const float4*)(gt  + idx);
        const float4 g1 = *(const float4*)(gt  + idx + 4);
        const float4 ua = *(const float4*)(pre + idx - uoff);
        const float4 ub = *(const float4*)(pre + idx + 4 - uoff);
        const float4 da = *(const float4*)(pre + idx + doff);
        const float4 db = *(const float4*)(pre + idx + 4 + doff);
        const float  lraw = pre[idx - loff];
        const float  rraw = pre[idx + roff];

        const bool hasu = (uoff != 0), hasd = (doff != 0);
        const float lft = (loff != 0) ? lraw : 0.0f;
        const float rgt = (roff != 0) ? rraw : 0.0f;

        const float c[8] = {c0.x, c0.y, c0.z, c0.w, c1.x, c1.y, c1.z, c1.w};
        const float g[8] = {g0.x, g0.y, g0.z, g0.w, g1.x, g1.y, g1.z, g1.w};
        const float u[8] = {hasu ? ua.x : 0.f, hasu ? ua.y : 0.f,
                            hasu ? ua.z : 0.f, hasu ? ua.w : 0.f,
                            hasu ? ub.x : 0.f, hasu ? ub.y : 0.f,
                            hasu ? ub.z : 0.f, hasu ? ub.w : 0.f};
        const float d[8] = {hasd ? da.x : 0.f, hasd ? da.y : 0.f,
                            hasd ? da.z : 0.f, hasd ? da.w : 0.f,
                            hasd ? db.x : 0.f, hasd ? db.y : 0.f,
                            hasd ? db.z : 0.f, hasd ? db.w : 0.f};
        const float lr[10] = {lft, c[0], c[1], c[2], c[3],
                              c[4], c[5], c[6], c[7], rgt};

        #pragma unroll
        for (int j = 0; j < 8; ++j) {
            const bool peak = (c[j] > lr[j]) && (c[j] > lr[j + 2]) &&
                              (c[j] > u[j]) && (c[j] > d[j]);
            float e = c[j] - g[j];
            e *= e;
            const float wt = (g[j] > 0.0f ? 5.0f : 1.0f) + (peak ? 1.0f : 0.0f);
            acc += wt * e;
        }
    }

    // ---- block reduction -> one partial per block ----
    #pragma unroll
    for (int off = 32; off > 0; off >>= 1) acc += __shfl_down(acc, off);
    const int wave = threadIdx.x >> 6;
    const int lane = threadIdx.x & 63;
    if (lane == 0) lred[wave] = acc;
    __syncthreads();
    if (threadIdx.x == 0) {
        float s = 0.0f;
        #pragma unroll
        for (int i = 0; i < BLOCK / 64; ++i) s += lred[i];
        ws_partials[blockIdx.x] = s;
    }
}

// ---------------------------------------------------------------------------
// Final reduce: NBLK partials -> scalar, scaled by 1/B.
// ---------------------------------------------------------------------------
__global__ __launch_bounds__(BLOCK) void reduce_kernel(
    const float* __restrict__ ws_partials,
    float* __restrict__ out) {
    float acc = 0.0f;
    for (int i = threadIdx.x; i < NBLK; i += BLOCK) acc += ws_partials[i];
    #pragma unroll
    for (int off = 32; off > 0; off >>= 1) acc += __shfl_down(acc, off);
    __shared__ float lred[BLOCK / 64];
    const int wave = threadIdx.x >> 6;
    const int lane = threadIdx.x & 63;
    if (lane == 0) lred[wave] = acc;
    __syncthreads();
    if (threadIdx.x == 0) {
        float s = 0.0f;
        #pragma unroll
        for (int i = 0; i < BLOCK / 64; ++i) s += lred[i];
        out[0] = s * (1.0f / (float)BDIM);
    }
}

extern "C" void kernel_launch(void* const* d_in, const int* in_sizes, int n_in,
                              void* d_out, int out_size, void* d_ws, size_t ws_size,
                              hipStream_t stream) {
    const float* pre  = (const float*)d_in[0];   // (16,1,768,768) fp32
    const float* gt   = (const float*)d_in[1];   // (16,1,768,768) fp32
    const int*   cors = (const int*)d_in[2];     // (16,512,2) int32
    float* out = (float*)d_out;                  // fp32 scalar
    float* partials = (float*)d_ws;              // NBLK floats of scratch

    fused_kernel<<<NBLK, BLOCK, 0, stream>>>(pre, gt, cors, partials);
    reduce_kernel<<<1, BLOCK, 0, stream>>>(partials, out);
}